// Round 1
// baseline (14972.748 us; speedup 1.0000x reference)
//
#include <hip/hip_runtime.h>
#include <math.h>

#define NLATg 181
#define NLONg 360
#define PIXg  65160        // 181*360
#define EMBg  256
#define MHIDg 512
#define PLANEg 8386816     // 181*181*256
#define LDIMg 32761        // 181*181

#define FLAG_GELU 1
#define FLAG_ACC  2

__device__ __forceinline__ float gelu_f(float x) {
    return 0.5f * x * (1.0f + erff(x * 0.70710678118654752440f));
}

// ---------------- init kernels (run every call; graph-capture safe) ----------------

// Orthonormal associated Legendre P[l][m][k], recurrence in fp64, stored fp32.
__global__ __launch_bounds__(256) void init_legendre(float* __restrict__ P) {
    int idx = blockIdx.x * 256 + threadIdx.x;
    if (idx >= 181 * 181) return;
    int m = idx / 181, k = idx % 181;
    double theta = M_PI * (double)k / 180.0;
    double ct = cos(theta), st = sin(theta);
    double pmm = sqrt(1.0 / (4.0 * M_PI));
    for (int j = 1; j <= m; ++j) pmm *= -sqrt((2.0 * j + 1.0) / (2.0 * j)) * st;
    for (int l = 0; l < m; ++l) P[(size_t)l * LDIMg + m * 181 + k] = 0.0f;
    P[(size_t)m * LDIMg + m * 181 + k] = (float)pmm;
    if (m + 1 < 181) {
        double pl1 = sqrt(2.0 * m + 3.0) * ct * pmm;
        P[(size_t)(m + 1) * LDIMg + m * 181 + k] = (float)pl1;
        double pl2 = pmm;
        for (int l = m + 2; l < 181; ++l) {
            double ll = l, mm = m;
            double a = sqrt((4.0 * ll * ll - 1.0) / (ll * ll - mm * mm));
            double b = sqrt(((2.0 * ll + 1.0) * (ll - 1.0 + mm) * (ll - 1.0 - mm)) /
                            ((2.0 * ll - 3.0) * (ll * ll - mm * mm)));
            double p = a * ct * pl1 - b * pl2;
            P[(size_t)l * LDIMg + m * 181 + k] = (float)p;
            pl2 = pl1; pl1 = p;
        }
    }
}

// Ecos[m][n]=cos(2pi m n/360), Esin[m][n]=-sin(...), Dt (iDFT^T, 362x360), wqs[k]=2*pi*w_k/360
__global__ __launch_bounds__(256) void init_trig(float* __restrict__ Ecos, float* __restrict__ Esin,
                                                 float* __restrict__ Dt, float* __restrict__ wqs) {
    int idx = blockIdx.x * 256 + threadIdx.x;
    if (idx < 181) {
        double theta = M_PI * (double)idx / 180.0;
        wqs[idx] = (float)(2.0 * M_PI * (M_PI / 180.0) * sin(theta) / 360.0);
    }
    if (idx >= 181 * 360) return;
    int m = idx / 360, n = idx % 360;
    int a = (m * n) % 360;           // exact angle reduction
    double ang = M_PI * (double)a / 180.0;
    double c = cos(ang), s = sin(ang);
    Ecos[idx] = (float)c;
    Esin[idx] = (float)(-s);
    double cm = (m == 0 || m == 180) ? 1.0 : 2.0;
    Dt[(size_t)m * 360 + n]         = (float)(cm * c);   // re rows
    Dt[(size_t)(181 + m) * 360 + n] = (float)(-cm * s);  // im rows
}

// ---------------- LayerNorm over channel dim (256), per pixel ----------------
__global__ __launch_bounds__(256) void ln_kernel(const float* __restrict__ X, float* __restrict__ Y) {
    int p0 = blockIdx.x * 64;
    int t = threadIdx.x;
    int ps = t & 63, cg = t >> 6;
    int p = p0 + ps;
    bool ok = p < PIXg;
    float sum = 0.f, sumsq = 0.f;
    if (ok) {
        for (int c = cg; c < EMBg; c += 4) {
            float v = X[(size_t)c * PIXg + p];
            sum += v; sumsq += v * v;
        }
    }
    __shared__ float s1[4][64];
    __shared__ float s2[4][64];
    s1[cg][ps] = sum; s2[cg][ps] = sumsq;
    __syncthreads();
    float tot  = s1[0][ps] + s1[1][ps] + s1[2][ps] + s1[3][ps];
    float tot2 = s2[0][ps] + s2[1][ps] + s2[2][ps] + s2[3][ps];
    float mu = tot * (1.0f / 256.0f);
    float var = tot2 * (1.0f / 256.0f) - mu * mu;
    float inv = rsqrtf(var + 1e-6f);
    if (ok) {
        for (int c = cg; c < EMBg; c += 4) {
            size_t offp = (size_t)c * PIXg + p;
            Y[offp] = (X[offp] - mu) * inv;
        }
    }
}

// x1 = gelu(Y + S + bias[c]), float4 over [256][PIX]
__global__ __launch_bounds__(256) void add_bias_gelu(const float* __restrict__ Y, const float* __restrict__ S,
                                                     const float* __restrict__ bsp, float* __restrict__ O) {
    int idx = blockIdx.x * 256 + threadIdx.x;   // float4 index, total 4,170,240
    int c = idx / 16290;                        // PIX/4 = 16290
    float b = bsp[c];
    float4 y = reinterpret_cast<const float4*>(Y)[idx];
    float4 s = reinterpret_cast<const float4*>(S)[idx];
    float4 o;
    o.x = gelu_f(y.x + s.x + b);
    o.y = gelu_f(y.y + s.y + b);
    o.z = gelu_f(y.z + s.z + b);
    o.w = gelu_f(y.w + s.w + b);
    reinterpret_cast<float4*>(O)[idx] = o;
}

// ---------------- general strided batched fp32 GEMM ----------------
// C[z][i][j] = sum_k A[z][i][k]*B[z][k][j]  (all strides in elements)
// epilogue: *zscale[z], +bias[i], +resid (C-strides), gelu, +=C
__global__ __launch_bounds__(256, 2) void gemm_f32(
    const float* __restrict__ A, long long Ars, long long Acs, long long Azs,
    const float* __restrict__ B, long long Brs, long long Bcs, long long Bzs,
    float* __restrict__ C, long long Crs, long long Ccs, long long Czs,
    const float* __restrict__ bias, const float* __restrict__ zscale,
    const float* __restrict__ resid,
    int M, int N, int K, int flags)
{
    const int z = blockIdx.z;
    A += (long long)z * Azs;
    B += (long long)z * Bzs;
    C += (long long)z * Czs;
    const int bm = blockIdx.y * 128;
    const int bn = blockIdx.x * 128;
    __shared__ float As[16][132];
    __shared__ float Bs[16][132];
    const int t = threadIdx.x;
    const int tx = t & 15, ty = t >> 4;
    const int r0 = ty * 8, c0 = tx * 8;
    float acc[8][8];
#pragma unroll
    for (int i = 0; i < 8; i++)
#pragma unroll
        for (int j = 0; j < 8; j++) acc[i][j] = 0.0f;

    for (int k0 = 0; k0 < K; k0 += 16) {
        // ---- stage A tile ----
        if (Acs == 1 && Ars != 1) {
            const int kk = t & 15;
            const int cb = t >> 4;
#pragma unroll
            for (int i = 0; i < 8; i++) {
                int row = cb + i * 16;
                int gr = bm + row, gk = k0 + kk;
                float v = 0.0f;
                if (gr < M && gk < K) v = A[(long long)gr * Ars + gk];
                As[kk][row] = v;
            }
        } else {
            const int row = t & 127;
            const int kb = t >> 7;
#pragma unroll
            for (int i = 0; i < 8; i++) {
                int kk = kb + i * 2;
                int gr = bm + row, gk = k0 + kk;
                float v = 0.0f;
                if (gr < M && gk < K) v = A[(long long)gr * Ars + (long long)gk * Acs];
                As[kk][row] = v;
            }
        }
        // ---- stage B tile ----
        if (Brs == 1 && Bcs != 1) {
            const int kk = t & 15;
            const int cb = t >> 4;
#pragma unroll
            for (int i = 0; i < 8; i++) {
                int col = cb + i * 16;
                int gc = bn + col, gk = k0 + kk;
                float v = 0.0f;
                if (gc < N && gk < K) v = B[gk + (long long)gc * Bcs];
                Bs[kk][col] = v;
            }
        } else {
            const int col = t & 127;
            const int kb = t >> 7;
#pragma unroll
            for (int i = 0; i < 8; i++) {
                int kk = kb + i * 2;
                int gc = bn + col, gk = k0 + kk;
                float v = 0.0f;
                if (gc < N && gk < K) v = B[(long long)gk * Brs + (long long)gc * Bcs];
                Bs[kk][col] = v;
            }
        }
        __syncthreads();
#pragma unroll
        for (int kk = 0; kk < 16; kk++) {
            float4 a0 = *reinterpret_cast<const float4*>(&As[kk][r0]);
            float4 a1 = *reinterpret_cast<const float4*>(&As[kk][r0 + 4]);
            float4 b0 = *reinterpret_cast<const float4*>(&Bs[kk][c0]);
            float4 b1 = *reinterpret_cast<const float4*>(&Bs[kk][c0 + 4]);
            float av[8] = {a0.x, a0.y, a0.z, a0.w, a1.x, a1.y, a1.z, a1.w};
            float bv[8] = {b0.x, b0.y, b0.z, b0.w, b1.x, b1.y, b1.z, b1.w};
#pragma unroll
            for (int i = 0; i < 8; i++)
#pragma unroll
                for (int j = 0; j < 8; j++)
                    acc[i][j] = fmaf(av[i], bv[j], acc[i][j]);
        }
        __syncthreads();
    }

    const float zs = zscale ? zscale[z] : 1.0f;
#pragma unroll
    for (int i = 0; i < 8; i++) {
        int gi = bm + r0 + i;
        if (gi < M) {
            float bval = bias ? bias[gi] : 0.0f;
#pragma unroll
            for (int j = 0; j < 8; j++) {
                int gj = bn + c0 + j;
                if (gj < N) {
                    long long offp = (long long)gi * Crs + (long long)gj * Ccs;
                    float v = acc[i][j] * zs + bval;
                    if (resid) v += resid[offp];
                    if (flags & FLAG_GELU) v = gelu_f(v);
                    if (flags & FLAG_ACC) v += C[offp];
                    C[offp] = v;
                }
            }
        }
    }
}

static inline void launch_gemm(hipStream_t s,
    const float* A, long long Ars, long long Acs, long long Azs,
    const float* B, long long Brs, long long Bcs, long long Bzs,
    float* C, long long Crs, long long Ccs, long long Czs,
    const float* bias, const float* zscale, const float* resid,
    int M, int N, int K, int Z, int flags)
{
    dim3 grid((N + 127) / 128, (M + 127) / 128, Z);
    hipLaunchKernelGGL(gemm_f32, grid, dim3(256), 0, s,
                       A, Ars, Acs, Azs, B, Brs, Bcs, Bzs, C, Crs, Ccs, Czs,
                       bias, zscale, resid, M, N, K, flags);
}

extern "C" void kernel_launch(void* const* d_in, const int* in_sizes, int n_in,
                              void* d_out, int out_size, void* d_ws, size_t ws_size,
                              hipStream_t stream)
{
    const float* x      = (const float*)d_in[0];
    const float* w_enc  = (const float*)d_in[1];
    const float* b_enc  = (const float*)d_in[2];
    const float* pos    = (const float*)d_in[3];
    const float* w_spec = (const float*)d_in[4];
    const float* b_spec = (const float*)d_in[5];
    const float* w_is   = (const float*)d_in[6];
    const float* b_is   = (const float*)d_in[7];
    const float* w_f1   = (const float*)d_in[8];
    const float* b_f1   = (const float*)d_in[9];
    const float* w_f2   = (const float*)d_in[10];
    const float* b_f2   = (const float*)d_in[11];
    const float* w_dec  = (const float*)d_in[12];
    const float* b_dec  = (const float*)d_in[13];
    float* out = (float*)d_out;
    float* ws  = (float*)d_ws;

    size_t off = 0;
    auto alloc = [&](size_t n) { size_t o = off; off += (n + 63) & ~(size_t)63; return o; };
    float* P    = ws + alloc((size_t)181 * 181 * 181);
    float* Ecos = ws + alloc((size_t)181 * 360);
    float* Esin = ws + alloc((size_t)181 * 360);
    float* Dt   = ws + alloc((size_t)362 * 360);
    float* wqs  = ws + alloc(181);
    float* S0   = ws + alloc((size_t)2 * PLANEg);   // F planes, then co planes
    float* S1   = ws + alloc((size_t)2 * PLANEg);   // coeff planes, then Fo planes (contig with S0)
    float* hbuf = ws + alloc((size_t)EMBg * PIXg);
    float* xn   = ws + alloc((size_t)EMBg * PIXg);
    float* tA   = ws + alloc((size_t)EMBg * PIXg);
    float* tB   = ws + alloc((size_t)EMBg * PIXg);
    float* hmlp = S0;   // 512*PIX floats spans S0..S1 (spectral bufs dead by MLP time)

    init_legendre<<<(181 * 181 + 255) / 256, 256, 0, stream>>>(P);
    init_trig<<<(181 * 360 + 255) / 256, 256, 0, stream>>>(Ecos, Esin, Dt, wqs);

    // encoder: h = w_enc*x + b_enc + pos_emb
    launch_gemm(stream, w_enc, 26, 1, 0,  x, PIXg, 1, 0,  hbuf, PIXg, 1, 0,
                b_enc, nullptr, pos, EMBg, PIXg, 26, 1, 0);

    for (int L = 0; L < 4; ++L) {
        const float* wsp = w_spec + (size_t)L * EMBg * EMBg * 181;
        const float* bsp = b_spec + (size_t)L * EMBg;
        const float* wis = w_is   + (size_t)L * EMBg * EMBg;
        const float* bis = b_is   + (size_t)L * EMBg;
        const float* wf1 = w_f1   + (size_t)L * MHIDg * EMBg;
        const float* bf1 = b_f1   + (size_t)L * MHIDg;
        const float* wf2 = w_f2   + (size_t)L * EMBg * MHIDg;
        const float* bf2 = b_f2   + (size_t)L * EMBg;

        // xn = LN(h)
        ln_kernel<<<1019, 256, 0, stream>>>(hbuf, xn);

        // DFT (z = latitude k): F[k][m][c] planes, quadrature*1/360 folded via zscale
        launch_gemm(stream, Ecos, 360, 1, 0,  xn, 1, PIXg, 360,  S0, 256, 1, 46336,
                    nullptr, wqs, nullptr, 181, 256, 360, 181, 0);
        launch_gemm(stream, Esin, 360, 1, 0,  xn, 1, PIXg, 360,  S0 + PLANEg, 256, 1, 46336,
                    nullptr, wqs, nullptr, 181, 256, 360, 181, 0);
        // Legendre analysis (z = m): coeff[m][l][c]
        launch_gemm(stream, P, LDIMg, 1, 181,  S0, 46336, 1, 256,  S1, 256, 1, 46336,
                    nullptr, nullptr, nullptr, 181, 256, 181, 181, 0);
        launch_gemm(stream, P, LDIMg, 1, 181,  S0 + PLANEg, 46336, 1, 256,  S1 + PLANEg, 256, 1, 46336,
                    nullptr, nullptr, nullptr, 181, 256, 181, 181, 0);
        // dhconv (z = l): co[m][l][o]
        launch_gemm(stream, wsp, 46336, 181, 1,  S1, 1, 46336, 256,  S0, 1, 46336, 256,
                    nullptr, nullptr, nullptr, 256, 181, 256, 181, 0);
        launch_gemm(stream, wsp, 46336, 181, 1,  S1 + PLANEg, 1, 46336, 256,  S0 + PLANEg, 1, 46336, 256,
                    nullptr, nullptr, nullptr, 256, 181, 256, 181, 0);
        // Legendre synthesis (z = m): Fo[reim][m][k][c] (re plane S1, im plane S1+PLANE)
        launch_gemm(stream, P, 1, LDIMg, 181,  S0, 256, 1, 46336,  S1, 256, 1, 46336,
                    nullptr, nullptr, nullptr, 181, 256, 181, 181, 0);
        launch_gemm(stream, P, 1, LDIMg, 181,  S0 + PLANEg, 256, 1, 46336,  S1 + PLANEg, 256, 1, 46336,
                    nullptr, nullptr, nullptr, 181, 256, 181, 181, 0);
        // iDFT (z = latitude k): y[c][pix] into tA, single GEMM K=362 over both planes
        launch_gemm(stream, S1, 1, 46336, 256,  Dt, 360, 1, 0,  tA, PIXg, 1, 360,
                    nullptr, nullptr, nullptr, 256, 360, 362, 181, 0);
        // inner skip: S = wis*xn + bis -> tB
        launch_gemm(stream, wis, 256, 1, 0,  xn, PIXg, 1, 0,  tB, PIXg, 1, 0,
                    bis, nullptr, nullptr, 256, PIXg, 256, 1, 0);
        // x1 = gelu(y + b_spec + S) -> tA
        add_bias_gelu<<<16290, 256, 0, stream>>>(tA, tB, bsp, tA);
        // x2 = LN(x1) -> tB
        ln_kernel<<<1019, 256, 0, stream>>>(tA, tB);
        // MLP fc1: hmlp = gelu(wf1*x2 + bf1)
        launch_gemm(stream, wf1, 256, 1, 0,  tB, PIXg, 1, 0,  hmlp, PIXg, 1, 0,
                    bf1, nullptr, nullptr, MHIDg, PIXg, 256, 1, FLAG_GELU);
        // MLP fc2 + residual xn -> h (next layer input)
        launch_gemm(stream, wf2, 512, 1, 0,  hmlp, PIXg, 1, 0,  hbuf, PIXg, 1, 0,
                    bf2, nullptr, xn, EMBg, PIXg, 512, 1, 0);
    }

    // decoder: out = w_dec[:, :256]*h + w_dec[:, 256:]*x + b_dec
    launch_gemm(stream, w_dec, 282, 1, 0,  hbuf, PIXg, 1, 0,  out, PIXg, 1, 0,
                b_dec, nullptr, nullptr, 26, PIXg, 256, 1, 0);
    launch_gemm(stream, w_dec + 256, 282, 1, 0,  x, PIXg, 1, 0,  out, PIXg, 1, 0,
                nullptr, nullptr, nullptr, 26, PIXg, 26, 1, FLAG_ACC);
}